// Round 5
// baseline (270.764 us; speedup 1.0000x reference)
//
#include <hip/hip_runtime.h>

#define T_TOK 2048
#define HID   1024
#define FFN   2048
#define NEXP  8
#define MAX_SLOTS 40

typedef __attribute__((ext_vector_type(8))) short bf16x8;
typedef __attribute__((ext_vector_type(4))) float f32x4;

__device__ __forceinline__ short f2bf(float f) {
    unsigned u = __builtin_bit_cast(unsigned, f);
    u = (u + 0x7fffu + ((u >> 16) & 1u)) >> 16;
    return (short)u;
}

__device__ __forceinline__ float gelu_exact(float x) {
    return 0.5f * x * (1.0f + erff(x * 0.70710678118654752f));
}

// async 16B global -> LDS DMA. LDS dest: wave-uniform base + lane*16.
__device__ __forceinline__ void async_cp16(const short* g, short* l) {
    __builtin_amdgcn_global_load_lds(
        (const __attribute__((address_space(1))) unsigned int*)g,
        (__attribute__((address_space(3))) unsigned int*)l, 16, 0, 0);
}

// ---- weight transpose body: W[e][K][N] f32 -> tiled bf16 panels -----------
// WT layout: [e][npanel=N/128][kpanel=K/64][kc=8][n=128][k8=8]  (8KB/k-panel)
__device__ __forceinline__ void wtrans_body(
        const float* __restrict__ W, short* __restrict__ WT,
        int K, int N, int e, int kblk, int nblk) {
    int tid = threadIdx.x;
    int w = tid >> 6, l = tid & 63;
    int kb = kblk * 32 + w * 8;               // this wave: 8 k-rows
    int n4 = nblk * 256 + l * 4;              // this lane: 4 n-cols
    const float* src = W + (size_t)e * K * N + (size_t)kb * N + n4;
    float4 v[8];
#pragma unroll
    for (int r = 0; r < 8; r++)
        v[r] = *(const float4*)(src + (size_t)r * N);
    int kpanel = kb >> 6;
    int kc = (kb >> 3) & 7;
    int npanel = n4 >> 7;
    int n_in = n4 & 127;
    int kpanels = K >> 6;
    short* dst = WT + (size_t)e * K * N
               + ((size_t)npanel * kpanels + kpanel) * 8192
               + kc * 1024 + n_in * 8;
#pragma unroll
    for (int j = 0; j < 4; j++) {
        bf16x8 o = {f2bf(((const float*)&v[0])[j]), f2bf(((const float*)&v[1])[j]),
                    f2bf(((const float*)&v[2])[j]), f2bf(((const float*)&v[3])[j]),
                    f2bf(((const float*)&v[4])[j]), f2bf(((const float*)&v[5])[j]),
                    f2bf(((const float*)&v[6])[j]), f2bf(((const float*)&v[7])[j])};
        *(bf16x8*)(dst + j * 8) = o;
    }
}

// ---- prep piece 1: W1 transpose -------------------------------------------
__global__ __launch_bounds__(256) void wtrans_w1_kernel(
        const float* __restrict__ W1, short* __restrict__ W1T) {
    int e = blockIdx.x >> 8, rem = blockIdx.x & 255;
    wtrans_body(W1, W1T, HID, FFN, e, rem & 31, rem >> 5);
}

// ---- prep piece 2: W2 transpose -------------------------------------------
__global__ __launch_bounds__(256) void wtrans_w2_kernel(
        const float* __restrict__ W2, short* __restrict__ W2T) {
    int e = blockIdx.x >> 8, rem = blockIdx.x & 255;
    wtrans_body(W2, W2T, FFN, HID, e, rem & 63, rem >> 6);
}

// ---- prep piece 3: xcvt | initout | bucket --------------------------------
__global__ __launch_bounds__(256) void misc_kernel(
        const float* __restrict__ x, const int* __restrict__ idx,
        const float* __restrict__ b2,
        short* __restrict__ xb, float* __restrict__ out,
        int* __restrict__ offs, int* __restrict__ cnts,
        int* __restrict__ tokl,
        int* __restrict__ slot_e, int* __restrict__ slot_t0) {
    int bx = blockIdx.x;
    int tid = threadIdx.x;
    if (bx < 1024) {                       // x f32 -> bf16
        int i = (bx * 256 + tid) * 8;
        float4 v0 = *(const float4*)(x + i);
        float4 v1 = *(const float4*)(x + i + 4);
        bf16x8 r = {f2bf(v0.x), f2bf(v0.y), f2bf(v0.z), f2bf(v0.w),
                    f2bf(v1.x), f2bf(v1.y), f2bf(v1.z), f2bf(v1.w)};
        *(bf16x8*)(xb + i) = r;
    } else if (bx < 3072) {                // out[t] = b2[idx[t]]  (split-K base)
        int t = bx - 1024;
        int e = idx[t];
        ((float4*)(out + (size_t)t * HID))[tid] =
            ((const float4*)(b2 + (size_t)e * HID))[tid];
    } else {                               // bucket + slot worklist (64/slot)
        __shared__ int c[NEXP], cur[NEXP], o[NEXP];
        if (tid < NEXP) { c[tid] = 0; cur[tid] = 0; }
        __syncthreads();
        for (int t = tid; t < T_TOK; t += 256) atomicAdd(&c[idx[t]], 1);
        __syncthreads();
        if (tid == 0) {
            int s = 0;
            for (int e = 0; e < NEXP; e++) { o[e] = s; s += c[e]; }
            int ns = 0;
            for (int e = 0; e < NEXP; e++)
                for (int t0 = 0; t0 < c[e]; t0 += 64) {
                    slot_e[ns] = e; slot_t0[ns] = t0; ns++;
                }
            for (; ns < MAX_SLOTS; ns++) slot_e[ns] = -1;
        }
        __syncthreads();
        if (tid < NEXP) { offs[tid] = o[tid]; cnts[tid] = c[tid]; }
        for (int t = tid; t < T_TOK; t += 256) {
            int e = idx[t];
            int p = o[e] + atomicAdd(&cur[e], 1);
            tokl[p] = t;
        }
    }
}

// ---- GEMM1: hg = gelu(xb_gathered @ W1T + b1) ------------------------------
// block 64m x 128n, BK=64, 3-deep counted-vmcnt pipeline (T3/T4).
// grid (FFN/128, MAX_SLOTS). LDS = 3 x 24KB.
__global__ __launch_bounds__(256) void gemm1_kernel(
        const short* __restrict__ xb, const short* __restrict__ W1T,
        const float* __restrict__ b1,
        const int* __restrict__ offs, const int* __restrict__ cnts,
        const int* __restrict__ tokl,
        const int* __restrict__ slot_e, const int* __restrict__ slot_t0,
        short* __restrict__ hg) {
    int s = blockIdx.y;
    int e = slot_e[s];
    if (e < 0) return;
    int t0 = slot_t0[s], count = cnts[e], off = offs[e];
    int n0 = blockIdx.x * 128;

    __shared__ short As[3 * 64 * 64];    // 3 x [64m][64k], chunk-rotated rows
    __shared__ short Bs[3 * 8 * 128 * 8];// 3 x [8kc][128n][8k] panel image
    __shared__ int stok[64];

    int tid = threadIdx.x;
    if (tid < 64) {
        int p = t0 + tid;
        stok[tid] = tokl[off + (p < count ? p : count - 1)];
    }
    __syncthreads();

    int w = tid >> 6, l = tid & 63, l15 = l & 15, quad = l >> 4;
    int wm = (w >> 1) * 32, wn = (w & 1) * 64;

    // A staging: 2 instrs/thread; instr i: row m = w*16+i*8+(l>>3), chunk l&7
    int m0 = w * 16 + (l >> 3), m1 = m0 + 8;
    int cs = l & 7;
    int c0 = (cs - m0) & 7, c1 = (cs - m1) & 7;   // chunk rotation by row
    const short* gA0 = xb + (size_t)stok[m0] * HID + c0 * 8;
    const short* gA1 = xb + (size_t)stok[m1] * HID + c1 * 8;
    int aoff = w * 1024 + l * 8;

    // B staging: 4 instrs/thread covering kc {2w,2w+1} x n-halves
    const short* Bpan = W1T + (size_t)e * (FFN * HID)
                      + (size_t)(n0 >> 7) * ((HID >> 6) * 8192);
    int bo0 = (2 * w) * 1024 + l * 8;
    int bo1 = bo0 + 1024;
    int bo2 = bo0 + 512;
    int bo3 = bo1 + 512;

    auto stage = [&](int buf, int kt) {
        const short* bp = Bpan + (size_t)kt * 8192;
        short* As_b = As + buf * 4096;
        short* Bs_b = Bs + buf * 8192;
        async_cp16(gA0 + kt * 64, As_b + aoff);
        async_cp16(gA1 + kt * 64, As_b + aoff + 512);
        async_cp16(bp + bo0, Bs_b + bo0);
        async_cp16(bp + bo1, Bs_b + bo1);
        async_cp16(bp + bo2, Bs_b + bo2);
        async_cp16(bp + bo3, Bs_b + bo3);
    };

    f32x4 acc[2][4];
#pragma unroll
    for (int i = 0; i < 2; i++)
#pragma unroll
        for (int j = 0; j < 4; j++) acc[i][j] = (f32x4){0.f, 0.f, 0.f, 0.f};

    const int KT = HID / 64;             // 16
    stage(0, 0); stage(1, 1); stage(2, 2);   // 18 loads in flight

    int buf = 0;
    for (int kt = 0; kt < KT; kt++) {
        // wait for OLDEST tile only; newer tiles stay in flight (T4)
        if (kt + 2 < KT)      asm volatile("s_waitcnt vmcnt(12)" ::: "memory");
        else if (kt + 1 < KT) asm volatile("s_waitcnt vmcnt(6)" ::: "memory");
        else                  asm volatile("s_waitcnt vmcnt(0)" ::: "memory");
        __builtin_amdgcn_s_barrier();    // tile kt visible to all waves

        const short* As_b = As + buf * 4096;
        const short* Bs_b = Bs + buf * 8192;
        bf16x8 a[2][2], b[2][4];
#pragma unroll
        for (int kk = 0; kk < 2; kk++) {
#pragma unroll
            for (int mt = 0; mt < 2; mt++) {
                int m = wm + mt * 16 + l15;
                a[kk][mt] = *(const bf16x8*)&As_b[m * 64 + (((kk * 4 + quad) + m) & 7) * 8];
            }
#pragma unroll
            for (int nt = 0; nt < 4; nt++) {
                int n = wn + nt * 16 + l15;
                b[kk][nt] = *(const bf16x8*)&Bs_b[(kk * 4 + quad) * 1024 + n * 8];
            }
        }
#pragma unroll
        for (int kk = 0; kk < 2; kk++)
#pragma unroll
            for (int mt = 0; mt < 2; mt++)
#pragma unroll
                for (int nt = 0; nt < 4; nt++)
                    acc[mt][nt] = __builtin_amdgcn_mfma_f32_16x16x32_bf16(
                        a[kk][mt], b[kk][nt], acc[mt][nt], 0, 0, 0);

        __builtin_amdgcn_sched_barrier(0);   // pin compute before the barrier
        __builtin_amdgcn_s_barrier();        // all waves done reading buf
        if (kt + 3 < KT) stage(buf, kt + 3); // refill freed buffer
        buf = buf + 1; if (buf == 3) buf = 0;
    }

    const float* b1e = b1 + e * FFN + n0;
#pragma unroll
    for (int mt = 0; mt < 2; mt++) {
        int rbase = wm + mt * 16 + quad * 4;
#pragma unroll
        for (int nt = 0; nt < 4; nt++) {
            int coln = wn + nt * 16 + l15;
            float bb = b1e[coln];
#pragma unroll
            for (int r = 0; r < 4; r++) {
                int p = t0 + rbase + r;
                if (p < count)
                    hg[(size_t)(off + p) * FFN + n0 + coln] =
                        f2bf(gelu_exact(acc[mt][nt][r] + bb));
            }
        }
    }
}

// ---- GEMM2: out[tok] += hg_gathered @ W2T  (split-K x2, atomic) ------------
// same 3-deep pipeline. grid (HID/128, MAX_SLOTS, 2).
__global__ __launch_bounds__(256) void gemm2_kernel(
        const short* __restrict__ hg, const short* __restrict__ W2T,
        const int* __restrict__ offs, const int* __restrict__ cnts,
        const int* __restrict__ tokl,
        const int* __restrict__ slot_e, const int* __restrict__ slot_t0,
        float* __restrict__ out) {
    int s = blockIdx.y;
    int e = slot_e[s];
    if (e < 0) return;
    int t0 = slot_t0[s], count = cnts[e], off = offs[e];
    int ks = blockIdx.z;
    int n0 = blockIdx.x * 128;

    __shared__ short As[3 * 64 * 64];
    __shared__ short Bs[3 * 8 * 128 * 8];

    int tid = threadIdx.x;
    int w = tid >> 6, l = tid & 63, l15 = l & 15, quad = l >> 4;
    int wm = (w >> 1) * 32, wn = (w & 1) * 64;

    int m0 = w * 16 + (l >> 3), m1 = m0 + 8;
    int cs = l & 7;
    int c0 = (cs - m0) & 7, c1 = (cs - m1) & 7;
    int g0 = off + (t0 + m0 < count ? t0 + m0 : count - 1);
    int g1 = off + (t0 + m1 < count ? t0 + m1 : count - 1);
    const short* gA0 = hg + (size_t)g0 * FFN + ks * 1024 + c0 * 8;
    const short* gA1 = hg + (size_t)g1 * FFN + ks * 1024 + c1 * 8;
    int aoff = w * 1024 + l * 8;

    const short* Bpan = W2T + (size_t)e * (FFN * HID)
                      + (size_t)(n0 >> 7) * ((FFN >> 6) * 8192)
                      + (size_t)ks * 16 * 8192;
    int bo0 = (2 * w) * 1024 + l * 8;
    int bo1 = bo0 + 1024;
    int bo2 = bo0 + 512;
    int bo3 = bo1 + 512;

    auto stage = [&](int buf, int kt) {
        const short* bp = Bpan + (size_t)kt * 8192;
        short* As_b = As + buf * 4096;
        short* Bs_b = Bs + buf * 8192;
        async_cp16(gA0 + kt * 64, As_b + aoff);
        async_cp16(gA1 + kt * 64, As_b + aoff + 512);
        async_cp16(bp + bo0, Bs_b + bo0);
        async_cp16(bp + bo1, Bs_b + bo1);
        async_cp16(bp + bo2, Bs_b + bo2);
        async_cp16(bp + bo3, Bs_b + bo3);
    };

    f32x4 acc[2][4];
#pragma unroll
    for (int i = 0; i < 2; i++)
#pragma unroll
        for (int j = 0; j < 4; j++) acc[i][j] = (f32x4){0.f, 0.f, 0.f, 0.f};

    const int KT = 16;
    stage(0, 0); stage(1, 1); stage(2, 2);

    int buf = 0;
    for (int kt = 0; kt < KT; kt++) {
        if (kt + 2 < KT)      asm volatile("s_waitcnt vmcnt(12)" ::: "memory");
        else if (kt + 1 < KT) asm volatile("s_waitcnt vmcnt(6)" ::: "memory");
        else                  asm volatile("s_waitcnt vmcnt(0)" ::: "memory");
        __builtin_amdgcn_s_barrier();

        const short* As_b = As + buf * 4096;
        const short* Bs_b = Bs + buf * 8192;
        bf16x8 a[2][2], b[2][4];
#pragma unroll
        for (int kk = 0; kk < 2; kk++) {
#pragma unroll
            for (int mt = 0; mt < 2; mt++) {
                int m = wm + mt * 16 + l15;
                a[kk][mt] = *(const bf16x8*)&As_b[m * 64 + (((kk * 4 + quad) + m) & 7) * 8];
            }
#pragma unroll
            for (int nt = 0; nt < 4; nt++) {
                int n = wn + nt * 16 + l15;
                b[kk][nt] = *(const bf16x8*)&Bs_b[(kk * 4 + quad) * 1024 + n * 8];
            }
        }
#pragma unroll
        for (int kk = 0; kk < 2; kk++)
#pragma unroll
            for (int mt = 0; mt < 2; mt++)
#pragma unroll
                for (int nt = 0; nt < 4; nt++)
                    acc[mt][nt] = __builtin_amdgcn_mfma_f32_16x16x32_bf16(
                        a[kk][mt], b[kk][nt], acc[mt][nt], 0, 0, 0);

        __builtin_amdgcn_sched_barrier(0);
        __builtin_amdgcn_s_barrier();
        if (kt + 3 < KT) stage(buf, kt + 3);
        buf = buf + 1; if (buf == 3) buf = 0;
    }

#pragma unroll
    for (int mt = 0; mt < 2; mt++) {
        int rbase = wm + mt * 16 + quad * 4;
#pragma unroll
        for (int nt = 0; nt < 4; nt++) {
            int coln = n0 + wn + nt * 16 + l15;
#pragma unroll
            for (int r = 0; r < 4; r++) {
                int p = t0 + rbase + r;
                if (p < count) {
                    int tok = tokl[off + p];
                    atomicAdd(out + (size_t)tok * HID + coln, acc[mt][nt][r]);
                }
            }
        }
    }
}

extern "C" void kernel_launch(void* const* d_in, const int* in_sizes, int n_in,
                              void* d_out, int out_size, void* d_ws, size_t ws_size,
                              hipStream_t stream) {
    const float* x   = (const float*)d_in[0];
    const int*   idx = (const int*)d_in[1];
    const float* W1  = (const float*)d_in[2];
    const float* b1  = (const float*)d_in[3];
    const float* W2  = (const float*)d_in[4];
    const float* b2  = (const float*)d_in[5];
    float* out = (float*)d_out;

    const size_t META = 32768;
    int*   offs    = (int*)d_ws;
    int*   cnts    = offs + 8;
    int*   tokl    = offs + 16;          // [2048]
    int*   slot_e  = offs + 16 + T_TOK;  // [MAX_SLOTS]
    int*   slot_t0 = slot_e + MAX_SLOTS;
    char*  base    = (char*)d_ws + META;
    short* xb  = (short*)base;                                    // 4 MB
    short* hg  = (short*)(base + (size_t)T_TOK * HID * 2);        // 8 MB
    short* W1T = (short*)(base + (size_t)T_TOK * HID * 2 + (size_t)T_TOK * FFN * 2);
    short* W2T = W1T + (size_t)NEXP * FFN * HID;                  // 32 MB each

    wtrans_w1_kernel<<<2048, 256, 0, stream>>>(W1, W1T);
    wtrans_w2_kernel<<<2048, 256, 0, stream>>>(W2, W2T);
    // misc: [0,1024) xcvt | [1024,3072) initout | 3072 bucket
    misc_kernel<<<3073, 256, 0, stream>>>(
        x, idx, b2, xb, out, offs, cnts, tokl, slot_e, slot_t0);

    gemm1_kernel<<<dim3(FFN / 128, MAX_SLOTS), 256, 0, stream>>>(
        xb, W1T, b1, offs, cnts, tokl, slot_e, slot_t0, hg);
    gemm2_kernel<<<dim3(HID / 128, MAX_SLOTS, 2), 256, 0, stream>>>(
        hg, W2T, offs, cnts, tokl, slot_e, slot_t0, out);
}

// Round 6
// 224.777 us; speedup vs baseline: 1.2046x; 1.2046x over previous
//
#include <hip/hip_runtime.h>

#define T_TOK 2048
#define HID   1024
#define FFN   2048
#define NEXP  8
#define MAX_SLOTS 40

typedef __attribute__((ext_vector_type(8))) short bf16x8;
typedef __attribute__((ext_vector_type(4))) float f32x4;

__device__ __forceinline__ short f2bf(float f) {
    unsigned u = __builtin_bit_cast(unsigned, f);
    u = (u + 0x7fffu + ((u >> 16) & 1u)) >> 16;
    return (short)u;
}

__device__ __forceinline__ float gelu_exact(float x) {
    return 0.5f * x * (1.0f + erff(x * 0.70710678118654752f));
}

// async 16B global -> LDS DMA. LDS dest: wave-uniform base + lane*16.
__device__ __forceinline__ void async_cp16(const short* g, short* l) {
    __builtin_amdgcn_global_load_lds(
        (const __attribute__((address_space(1))) unsigned int*)g,
        (__attribute__((address_space(3))) unsigned int*)l, 16, 0, 0);
}

// ---- weight transpose body: W[e][K][N] f32 -> tiled bf16 panels -----------
// WT layout: [e][npanel=N/128][kpanel=K/64][kc=8][n=128][k8=8]  (8KB/k-panel)
__device__ __forceinline__ void wtrans_body(
        const float* __restrict__ W, short* __restrict__ WT,
        int K, int N, int e, int kblk, int nblk) {
    int tid = threadIdx.x;
    int w = tid >> 6, l = tid & 63;
    int kb = kblk * 32 + w * 8;               // this wave: 8 k-rows
    int n4 = nblk * 256 + l * 4;              // this lane: 4 n-cols
    const float* src = W + (size_t)e * K * N + (size_t)kb * N + n4;
    float4 v[8];
#pragma unroll
    for (int r = 0; r < 8; r++)
        v[r] = *(const float4*)(src + (size_t)r * N);
    int kpanel = kb >> 6;
    int kc = (kb >> 3) & 7;
    int npanel = n4 >> 7;
    int n_in = n4 & 127;
    int kpanels = K >> 6;
    short* dst = WT + (size_t)e * K * N
               + ((size_t)npanel * kpanels + kpanel) * 8192
               + kc * 1024 + n_in * 8;
#pragma unroll
    for (int j = 0; j < 4; j++) {
        bf16x8 o = {f2bf(((const float*)&v[0])[j]), f2bf(((const float*)&v[1])[j]),
                    f2bf(((const float*)&v[2])[j]), f2bf(((const float*)&v[3])[j]),
                    f2bf(((const float*)&v[4])[j]), f2bf(((const float*)&v[5])[j]),
                    f2bf(((const float*)&v[6])[j]), f2bf(((const float*)&v[7])[j])};
        *(bf16x8*)(dst + j * 8) = o;
    }
}

// ---- K1: W1-transpose | xcvt | initout | bucket  (all gemm1 prerequisites) -
__global__ __launch_bounds__(256) void prep1_kernel(
        const float* __restrict__ x, const int* __restrict__ idx,
        const float* __restrict__ b2, const float* __restrict__ W1,
        short* __restrict__ xb, float* __restrict__ out,
        short* __restrict__ W1T,
        int* __restrict__ offs, int* __restrict__ cnts,
        int* __restrict__ tokl,
        int* __restrict__ slot_e, int* __restrict__ slot_t0) {
    int bx = blockIdx.x;
    int tid = threadIdx.x;
    if (bx < 2048) {                       // W1: 8e x (32 kblk x 8 nblk)
        int e = bx >> 8, rem = bx & 255;
        wtrans_body(W1, W1T, HID, FFN, e, rem & 31, rem >> 5);
    } else if (bx < 3072) {                // x f32 -> bf16
        int i = ((bx - 2048) * 256 + tid) * 8;
        float4 v0 = *(const float4*)(x + i);
        float4 v1 = *(const float4*)(x + i + 4);
        bf16x8 r = {f2bf(v0.x), f2bf(v0.y), f2bf(v0.z), f2bf(v0.w),
                    f2bf(v1.x), f2bf(v1.y), f2bf(v1.z), f2bf(v1.w)};
        *(bf16x8*)(xb + i) = r;
    } else if (bx < 5120) {                // out[t] = b2[idx[t]]  (split-K base)
        int t = bx - 3072;
        int e = idx[t];
        ((float4*)(out + (size_t)t * HID))[tid] =
            ((const float4*)(b2 + (size_t)e * HID))[tid];
    } else {                               // bucket + slot worklist (64/slot)
        __shared__ int c[NEXP], cur[NEXP], o[NEXP];
        if (tid < NEXP) { c[tid] = 0; cur[tid] = 0; }
        __syncthreads();
        for (int t = tid; t < T_TOK; t += 256) atomicAdd(&c[idx[t]], 1);
        __syncthreads();
        if (tid == 0) {
            int s = 0;
            for (int e = 0; e < NEXP; e++) { o[e] = s; s += c[e]; }
            int ns = 0;
            for (int e = 0; e < NEXP; e++)
                for (int t0 = 0; t0 < c[e]; t0 += 64) {
                    slot_e[ns] = e; slot_t0[ns] = t0; ns++;
                }
            for (; ns < MAX_SLOTS; ns++) slot_e[ns] = -1;
        }
        __syncthreads();
        if (tid < NEXP) { offs[tid] = o[tid]; cnts[tid] = c[tid]; }
        for (int t = tid; t < T_TOK; t += 256) {
            int e = idx[t];
            int p = o[e] + atomicAdd(&cur[e], 1);
            tokl[p] = t;
        }
    }
}

// ---- K2: gemm1 blocks (bx<640) + W2-transpose blocks (bx>=640) -------------
// gemm1: block 64m x 128n, BK=64, single-buf serial loop [r0, best known].
// W2-trans blocks fill the CU slots the latency-bound gemm1 leaves idle.
__global__ __launch_bounds__(256) void gemm1_w2_kernel(
        const short* __restrict__ xb, const short* __restrict__ W1T,
        const float* __restrict__ b1,
        const int* __restrict__ offs, const int* __restrict__ cnts,
        const int* __restrict__ tokl,
        const int* __restrict__ slot_e, const int* __restrict__ slot_t0,
        short* __restrict__ hg,
        const float* __restrict__ W2, short* __restrict__ W2T) {
    __shared__ short As[64 * 64];        // [64m][64k], 128B rows, chunk-rotated
    __shared__ short Bs[8 * 128 * 8];    // [8kc][128n][8k] linear panel image
    __shared__ int stok[64];

    int bx = blockIdx.x;
    if (bx >= 640) {                       // W2: 8e x (64 kblk x 4 nblk)
        int b = bx - 640;
        int e = b >> 8, rem = b & 255;
        wtrans_body(W2, W2T, FFN, HID, e, rem & 63, rem >> 6);
        return;
    }

    int s = bx >> 4;
    int e = slot_e[s];
    if (e < 0) return;
    int t0 = slot_t0[s], count = cnts[e], off = offs[e];
    int n0 = (bx & 15) * 128;

    int tid = threadIdx.x;
    if (tid < 64) {
        int p = t0 + tid;
        stok[tid] = tokl[off + (p < count ? p : count - 1)];
    }
    __syncthreads();

    int w = tid >> 6, l = tid & 63, l15 = l & 15, quad = l >> 4;
    int wm = (w >> 1) * 32, wn = (w & 1) * 64;

    // A staging: 2 instrs/wave; instr i: row m = w*16+i*8+(l>>3), slot chunk l&7
    int m0 = w * 16 + (l >> 3), m1 = m0 + 8;
    int cs = l & 7;
    int c0 = (cs - m0) & 7, c1 = (cs - m1) & 7;   // chunk rotation by row
    const short* gA0 = xb + (size_t)stok[m0] * HID + c0 * 8;
    const short* gA1 = xb + (size_t)stok[m1] * HID + c1 * 8;
    short* lA0 = As + w * 1024 + l * 8;
    short* lA1 = lA0 + 512;

    // B staging: 4 instrs/wave covering kc {2w,2w+1} x n-halves
    const short* Bpan = W1T + (size_t)e * (FFN * HID)
                      + (size_t)(n0 >> 7) * ((HID >> 6) * 8192);
    int bo0 = (2 * w) * 1024 + l * 8;
    int bo1 = bo0 + 1024;
    int bo2 = bo0 + 512;
    int bo3 = bo1 + 512;

    f32x4 acc[2][4];
#pragma unroll
    for (int i = 0; i < 2; i++)
#pragma unroll
        for (int j = 0; j < 4; j++) acc[i][j] = (f32x4){0.f, 0.f, 0.f, 0.f};

    for (int kt = 0; kt < HID / 64; kt++) {
        const short* bp = Bpan + kt * 8192;
        async_cp16(gA0, lA0);
        async_cp16(gA1, lA1);
        async_cp16(bp + bo0, Bs + bo0);
        async_cp16(bp + bo1, Bs + bo1);
        async_cp16(bp + bo2, Bs + bo2);
        async_cp16(bp + bo3, Bs + bo3);
        gA0 += 64; gA1 += 64;
        __syncthreads();
        bf16x8 a[2][2], b[2][4];
#pragma unroll
        for (int kk = 0; kk < 2; kk++) {
#pragma unroll
            for (int mt = 0; mt < 2; mt++) {
                int m = wm + mt * 16 + l15;
                a[kk][mt] = *(const bf16x8*)&As[m * 64 + (((kk * 4 + quad) + m) & 7) * 8];
            }
#pragma unroll
            for (int nt = 0; nt < 4; nt++) {
                int n = wn + nt * 16 + l15;
                b[kk][nt] = *(const bf16x8*)&Bs[(kk * 4 + quad) * 1024 + n * 8];
            }
        }
#pragma unroll
        for (int kk = 0; kk < 2; kk++)
#pragma unroll
            for (int mt = 0; mt < 2; mt++)
#pragma unroll
                for (int nt = 0; nt < 4; nt++)
                    acc[mt][nt] = __builtin_amdgcn_mfma_f32_16x16x32_bf16(
                        a[kk][mt], b[kk][nt], acc[mt][nt], 0, 0, 0);
        __syncthreads();
    }

    const float* b1e = b1 + e * FFN + n0;
#pragma unroll
    for (int mt = 0; mt < 2; mt++) {
        int rbase = wm + mt * 16 + quad * 4;
#pragma unroll
        for (int nt = 0; nt < 4; nt++) {
            int coln = wn + nt * 16 + l15;
            float bb = b1e[coln];
#pragma unroll
            for (int r = 0; r < 4; r++) {
                int p = t0 + rbase + r;
                if (p < count)
                    hg[(size_t)(off + p) * FFN + n0 + coln] =
                        f2bf(gelu_exact(acc[mt][nt][r] + bb));
            }
        }
    }
}

// ---- K3: GEMM2: out[tok] += hg_gathered @ W2T  (split-K x2, atomic) --------
// grid (HID/128, MAX_SLOTS, 2).   [r0 structure, best known]
__global__ __launch_bounds__(256) void gemm2_kernel(
        const short* __restrict__ hg, const short* __restrict__ W2T,
        const int* __restrict__ offs, const int* __restrict__ cnts,
        const int* __restrict__ tokl,
        const int* __restrict__ slot_e, const int* __restrict__ slot_t0,
        float* __restrict__ out) {
    int s = blockIdx.y;
    int e = slot_e[s];
    if (e < 0) return;
    int t0 = slot_t0[s], count = cnts[e], off = offs[e];
    int ks = blockIdx.z;
    int n0 = blockIdx.x * 128;

    __shared__ short As[64 * 64];
    __shared__ short Bs[8 * 128 * 8];

    int tid = threadIdx.x;
    int w = tid >> 6, l = tid & 63, l15 = l & 15, quad = l >> 4;
    int wm = (w >> 1) * 32, wn = (w & 1) * 64;

    int m0 = w * 16 + (l >> 3), m1 = m0 + 8;
    int cs = l & 7;
    int c0 = (cs - m0) & 7, c1 = (cs - m1) & 7;
    int g0 = off + (t0 + m0 < count ? t0 + m0 : count - 1);
    int g1 = off + (t0 + m1 < count ? t0 + m1 : count - 1);
    const short* gA0 = hg + (size_t)g0 * FFN + ks * 1024 + c0 * 8;
    const short* gA1 = hg + (size_t)g1 * FFN + ks * 1024 + c1 * 8;
    short* lA0 = As + w * 1024 + l * 8;
    short* lA1 = lA0 + 512;

    const short* Bpan = W2T + (size_t)e * (FFN * HID)
                      + (size_t)(n0 >> 7) * ((FFN >> 6) * 8192)
                      + (size_t)ks * 16 * 8192;
    int bo0 = (2 * w) * 1024 + l * 8;
    int bo1 = bo0 + 1024;
    int bo2 = bo0 + 512;
    int bo3 = bo1 + 512;

    f32x4 acc[2][4];
#pragma unroll
    for (int i = 0; i < 2; i++)
#pragma unroll
        for (int j = 0; j < 4; j++) acc[i][j] = (f32x4){0.f, 0.f, 0.f, 0.f};

    for (int kt = 0; kt < 16; kt++) {
        const short* bp = Bpan + kt * 8192;
        async_cp16(gA0, lA0);
        async_cp16(gA1, lA1);
        async_cp16(bp + bo0, Bs + bo0);
        async_cp16(bp + bo1, Bs + bo1);
        async_cp16(bp + bo2, Bs + bo2);
        async_cp16(bp + bo3, Bs + bo3);
        gA0 += 64; gA1 += 64;
        __syncthreads();
        bf16x8 a[2][2], b[2][4];
#pragma unroll
        for (int kk = 0; kk < 2; kk++) {
#pragma unroll
            for (int mt = 0; mt < 2; mt++) {
                int m = wm + mt * 16 + l15;
                a[kk][mt] = *(const bf16x8*)&As[m * 64 + (((kk * 4 + quad) + m) & 7) * 8];
            }
#pragma unroll
            for (int nt = 0; nt < 4; nt++) {
                int n = wn + nt * 16 + l15;
                b[kk][nt] = *(const bf16x8*)&Bs[(kk * 4 + quad) * 1024 + n * 8];
            }
        }
#pragma unroll
        for (int kk = 0; kk < 2; kk++)
#pragma unroll
            for (int mt = 0; mt < 2; mt++)
#pragma unroll
                for (int nt = 0; nt < 4; nt++)
                    acc[mt][nt] = __builtin_amdgcn_mfma_f32_16x16x32_bf16(
                        a[kk][mt], b[kk][nt], acc[mt][nt], 0, 0, 0);
        __syncthreads();
    }

#pragma unroll
    for (int mt = 0; mt < 2; mt++) {
        int rbase = wm + mt * 16 + quad * 4;
#pragma unroll
        for (int nt = 0; nt < 4; nt++) {
            int coln = n0 + wn + nt * 16 + l15;
#pragma unroll
            for (int r = 0; r < 4; r++) {
                int p = t0 + rbase + r;
                if (p < count) {
                    int tok = tokl[off + p];
                    atomicAdd(out + (size_t)tok * HID + coln, acc[mt][nt][r]);
                }
            }
        }
    }
}

extern "C" void kernel_launch(void* const* d_in, const int* in_sizes, int n_in,
                              void* d_out, int out_size, void* d_ws, size_t ws_size,
                              hipStream_t stream) {
    const float* x   = (const float*)d_in[0];
    const int*   idx = (const int*)d_in[1];
    const float* W1  = (const float*)d_in[2];
    const float* b1  = (const float*)d_in[3];
    const float* W2  = (const float*)d_in[4];
    const float* b2  = (const float*)d_in[5];
    float* out = (float*)d_out;

    const size_t META = 32768;
    int*   offs    = (int*)d_ws;
    int*   cnts    = offs + 8;
    int*   tokl    = offs + 16;          // [2048]
    int*   slot_e  = offs + 16 + T_TOK;  // [MAX_SLOTS]
    int*   slot_t0 = slot_e + MAX_SLOTS;
    char*  base    = (char*)d_ws + META;
    short* xb  = (short*)base;                                    // 4 MB
    short* hg  = (short*)(base + (size_t)T_TOK * HID * 2);        // 8 MB
    short* W1T = (short*)(base + (size_t)T_TOK * HID * 2 + (size_t)T_TOK * FFN * 2);
    short* W2T = W1T + (size_t)NEXP * FFN * HID;                  // 32 MB each

    // K1: [0,2048) W1-trans | [2048,3072) xcvt | [3072,5120) initout | 5120 bucket
    prep1_kernel<<<5121, 256, 0, stream>>>(
        x, idx, b2, W1, xb, out, W1T, offs, cnts, tokl, slot_e, slot_t0);

    // K2: [0,640) gemm1 (16 nblk x 40 slots) | [640,2688) W2-trans
    gemm1_w2_kernel<<<2688, 256, 0, stream>>>(
        xb, W1T, b1, offs, cnts, tokl, slot_e, slot_t0, hg, W2, W2T);

    // K3: gemm2 split-K x2
    gemm2_kernel<<<dim3(HID / 128, MAX_SLOTS, 2), 256, 0, stream>>>(
        hg, W2T, offs, cnts, tokl, slot_e, slot_t0, out);
}